// Round 1
// baseline (2217.579 us; speedup 1.0000x reference)
//
#include <hip/hip_runtime.h>
#include <math.h>

#define NN 100000
#define NE 3200000

#define FMA4(a, s, v) { (a).x += (s)*(v).x; (a).y += (s)*(v).y; (a).z += (s)*(v).z; (a).w += (s)*(v).w; }

// ---------------- layer-1 node transform: y0=x@W0, y1=x@W1, xr=x@R  (32->32)
__global__ __launch_bounds__(256) void transform1_k(
    const float* __restrict__ x, const float* __restrict__ W,   // W: [2,32,32]
    const float* __restrict__ R,
    float* __restrict__ y0, float* __restrict__ y1, float* __restrict__ xr)
{
    __shared__ float W0s[1024], W1s[1024], Rs[1024];
    __shared__ float xs[32 * 33];                 // +1 pad: kill 8-way bank conflict
    int tid = threadIdx.x;
    for (int i = tid; i < 1024; i += 256) {
        W0s[i] = W[i];
        W1s[i] = W[1024 + i];
        Rs[i]  = R[i];
    }
    int nb = blockIdx.x * 32;
    for (int i = tid; i < 1024; i += 256) {
        int n = nb + (i >> 5);
        xs[(i >> 5) * 33 + (i & 31)] = (n < NN) ? x[n * 32 + (i & 31)] : 0.f;
    }
    __syncthreads();
    int local = tid >> 3, c = tid & 7;            // 32 nodes/block, 8 lanes/node
    int n = nb + local;
    float4 a0 = make_float4(0.f, 0.f, 0.f, 0.f), a1 = a0, a2 = a0;
    #pragma unroll
    for (int k = 0; k < 32; k++) {
        float xk = xs[local * 33 + k];
        float4 w0 = ((const float4*)W0s)[k * 8 + c];
        float4 w1 = ((const float4*)W1s)[k * 8 + c];
        float4 r  = ((const float4*)Rs)[k * 8 + c];
        FMA4(a0, xk, w0); FMA4(a1, xk, w1); FMA4(a2, xk, r);
    }
    if (n < NN) {
        ((float4*)y0)[n * 8 + c] = a0;
        ((float4*)y1)[n * 8 + c] = a1;
        ((float4*)xr)[n * 8 + c] = a2;
    }
}

// ---------------- layer-2 node transform: z0=h@W0, z1=h@W1, hr=h@R  (32->16)
__global__ __launch_bounds__(256) void transform2_k(
    const float* __restrict__ h, const float* __restrict__ W,   // W: [2,32,16]
    const float* __restrict__ R,
    float* __restrict__ z0, float* __restrict__ z1, float* __restrict__ hr)
{
    __shared__ float W0s[512], W1s[512], Rs[512];
    __shared__ float xs[64 * 33];
    int tid = threadIdx.x;
    for (int i = tid; i < 512; i += 256) {
        W0s[i] = W[i];
        W1s[i] = W[512 + i];
        Rs[i]  = R[i];
    }
    int nb = blockIdx.x * 64;
    for (int i = tid; i < 2048; i += 256) {
        int n = nb + (i >> 5);
        xs[(i >> 5) * 33 + (i & 31)] = (n < NN) ? h[n * 32 + (i & 31)] : 0.f;
    }
    __syncthreads();
    int local = tid >> 2, c = tid & 3;            // 64 nodes/block, 4 lanes/node
    int n = nb + local;
    float4 a0 = make_float4(0.f, 0.f, 0.f, 0.f), a1 = a0, a2 = a0;
    #pragma unroll
    for (int k = 0; k < 32; k++) {
        float xk = xs[local * 33 + k];
        float4 w0 = ((const float4*)W0s)[k * 4 + c];
        float4 w1 = ((const float4*)W1s)[k * 4 + c];
        float4 r  = ((const float4*)Rs)[k * 4 + c];
        FMA4(a0, xk, w0); FMA4(a1, xk, w1); FMA4(a2, xk, r);
    }
    if (n < NN) {
        ((float4*)z0)[n * 4 + c] = a0;
        ((float4*)z1)[n * 4 + c] = a1;
        ((float4*)hr)[n * 4 + c] = a2;
    }
}

// ---------------- edge pass layer 1: agg[dst] += (1-u)*y0[src] + u*y1[src]; cnt[dst]++
__global__ __launch_bounds__(256) void edge1_k(
    const int* __restrict__ ei, const float* __restrict__ ea,
    const float* __restrict__ y0, const float* __restrict__ y1,
    float* __restrict__ agg, float* __restrict__ cnt)
{
    int tid = blockIdx.x * 256 + threadIdx.x;     // NE*8 threads
    int e = tid >> 3, c = tid & 7;
    if (e >= NE) return;
    int s = ei[e];
    int d = ei[NE + e];
    float u = ea[e];
    u = fminf(fmaxf(u, 0.f), 1.f);
    float w0 = 1.f - u;
    float4 a = ((const float4*)y0)[s * 8 + c];
    float4 b = ((const float4*)y1)[s * 8 + c];
    float4 m;
    m.x = w0 * a.x + u * b.x;
    m.y = w0 * a.y + u * b.y;
    m.z = w0 * a.z + u * b.z;
    m.w = w0 * a.w + u * b.w;
    float* o = agg + d * 32 + c * 4;
    atomicAdd(o + 0, m.x);
    atomicAdd(o + 1, m.y);
    atomicAdd(o + 2, m.z);
    atomicAdd(o + 3, m.w);
    if (c == 0) atomicAdd(cnt + d, 1.f);
}

// ---------------- edge pass layer 2 (16 features, cnt reused)
__global__ __launch_bounds__(256) void edge2_k(
    const int* __restrict__ ei, const float* __restrict__ ea,
    const float* __restrict__ z0, const float* __restrict__ z1,
    float* __restrict__ agg)
{
    int tid = blockIdx.x * 256 + threadIdx.x;     // NE*4 threads
    int e = tid >> 2, c = tid & 3;
    if (e >= NE) return;
    int s = ei[e];
    int d = ei[NE + e];
    float u = ea[e];
    u = fminf(fmaxf(u, 0.f), 1.f);
    float w0 = 1.f - u;
    float4 a = ((const float4*)z0)[s * 4 + c];
    float4 b = ((const float4*)z1)[s * 4 + c];
    float4 m;
    m.x = w0 * a.x + u * b.x;
    m.y = w0 * a.y + u * b.y;
    m.z = w0 * a.z + u * b.z;
    m.w = w0 * a.w + u * b.w;
    float* o = agg + d * 16 + c * 4;
    atomicAdd(o + 0, m.x);
    atomicAdd(o + 1, m.y);
    atomicAdd(o + 2, m.z);
    atomicAdd(o + 3, m.w);
}

// ---------------- finish layer 1: h = relu(agg/max(cnt,1) + xr + b1), in place over xr
__global__ __launch_bounds__(256) void finish1_k(
    const float* __restrict__ agg, const float* __restrict__ cnt,
    const float* __restrict__ b, float* __restrict__ hx)
{
    int tid = blockIdx.x * 256 + threadIdx.x;     // NN*8 threads
    int n = tid >> 3, c = tid & 7;
    if (n >= NN) return;
    float inv = 1.f / fmaxf(cnt[n], 1.f);
    float4 a  = ((const float4*)agg)[n * 8 + c];
    float4 r  = ((const float4*)hx)[n * 8 + c];
    float4 bb = ((const float4*)b)[c];
    float4 h;
    h.x = fmaxf(a.x * inv + r.x + bb.x, 0.f);
    h.y = fmaxf(a.y * inv + r.y + bb.y, 0.f);
    h.z = fmaxf(a.z * inv + r.z + bb.z, 0.f);
    h.w = fmaxf(a.w * inv + r.w + bb.w, 0.f);
    ((float4*)hx)[n * 8 + c] = h;
}

// ---------------- finish layer 2: out = log_softmax(agg/max(cnt,1) + hr + b2)
__global__ __launch_bounds__(256) void finish2_k(
    const float* __restrict__ agg, const float* __restrict__ cnt,
    const float* __restrict__ hr, const float* __restrict__ b,
    float* __restrict__ out)
{
    int n = blockIdx.x * 256 + threadIdx.x;       // NN threads
    if (n >= NN) return;
    float inv = 1.f / fmaxf(cnt[n], 1.f);
    float4 o[4];
    #pragma unroll
    for (int q = 0; q < 4; q++) {
        float4 a  = ((const float4*)agg)[n * 4 + q];
        float4 r  = ((const float4*)hr)[n * 4 + q];
        float4 bb = ((const float4*)b)[q];
        o[q].x = a.x * inv + r.x + bb.x;
        o[q].y = a.y * inv + r.y + bb.y;
        o[q].z = a.z * inv + r.z + bb.z;
        o[q].w = a.w * inv + r.w + bb.w;
    }
    float m = o[0].x;
    #pragma unroll
    for (int q = 0; q < 4; q++) {
        m = fmaxf(m, o[q].x); m = fmaxf(m, o[q].y);
        m = fmaxf(m, o[q].z); m = fmaxf(m, o[q].w);
    }
    float sum = 0.f;
    #pragma unroll
    for (int q = 0; q < 4; q++) {
        sum += expf(o[q].x - m) + expf(o[q].y - m) +
               expf(o[q].z - m) + expf(o[q].w - m);
    }
    float ls = m + logf(sum);
    #pragma unroll
    for (int q = 0; q < 4; q++) {
        float4 v;
        v.x = o[q].x - ls; v.y = o[q].y - ls;
        v.z = o[q].z - ls; v.w = o[q].w - ls;
        ((float4*)out)[n * 4 + q] = v;
    }
}

extern "C" void kernel_launch(void* const* d_in, const int* in_sizes, int n_in,
                              void* d_out, int out_size, void* d_ws, size_t ws_size,
                              hipStream_t stream) {
    const float* x     = (const float*)d_in[0];
    const int*   ei    = (const int*)d_in[1];     // [2, NE] int
    const float* ea    = (const float*)d_in[2];   // [NE, 1]
    const float* W1    = (const float*)d_in[3];   // [2,32,32]
    const float* root1 = (const float*)d_in[4];   // [32,32]
    const float* b1    = (const float*)d_in[5];   // [32]
    const float* W2    = (const float*)d_in[6];   // [2,32,16]
    const float* root2 = (const float*)d_in[7];   // [32,16]
    const float* b2    = (const float*)d_in[8];   // [16]
    float* out = (float*)d_out;

    // workspace layout (floats). agg1|cnt|agg2 contiguous -> single memset.
    float* ws   = (float*)d_ws;
    float* agg1 = ws;                       // NN*32
    float* cnt  = agg1 + (size_t)NN * 32;   // NN
    float* agg2 = cnt + NN;                 // NN*16
    float* y0   = agg2 + (size_t)NN * 16;   // NN*32
    float* y1   = y0 + (size_t)NN * 32;     // NN*32
    float* xr_h = y1 + (size_t)NN * 32;     // NN*32 (xr, then h in place)
    // layer-2 aliases into dead y0/y1 space:
    float* z0 = y0;                         // NN*16
    float* hr = y0 + (size_t)NN * 16;       // NN*16
    float* z1 = y1;                         // NN*16

    hipMemsetAsync(ws, 0, (size_t)NN * 49 * sizeof(float), stream);

    transform1_k<<<(NN + 31) / 32, 256, 0, stream>>>(x, W1, root1, y0, y1, xr_h);
    edge1_k<<<(NE * 8) / 256, 256, 0, stream>>>(ei, ea, y0, y1, agg1, cnt);
    finish1_k<<<(NN * 8 + 255) / 256, 256, 0, stream>>>(agg1, cnt, b1, xr_h);
    transform2_k<<<(NN + 63) / 64, 256, 0, stream>>>(xr_h, W2, root2, z0, z1, hr);
    edge2_k<<<(NE * 4) / 256, 256, 0, stream>>>(ei, ea, z0, z1, agg2);
    finish2_k<<<(NN + 255) / 256, 256, 0, stream>>>(agg2, cnt, hr, b2, out);
}

// Round 2
// 711.107 us; speedup vs baseline: 3.1185x; 3.1185x over previous
//
#include <hip/hip_runtime.h>
#include <math.h>

#define NN 100000
#define NE 3200000
#define NB ((NN + 255) / 256)   // 391 scan blocks

#define FMA4(a, s, v) { (a).x += (s)*(v).x; (a).y += (s)*(v).y; (a).z += (s)*(v).z; (a).w += (s)*(v).w; }

// ---------------- CSR build ----------------
__global__ __launch_bounds__(256) void hist_k(const int* __restrict__ ei, int* __restrict__ deg) {
    int e = blockIdx.x * 256 + threadIdx.x;
    if (e >= NE) return;
    atomicAdd(deg + ei[NE + e], 1);
}

// per-block exclusive scan of deg -> off (block-local), block totals -> bsum
__global__ __launch_bounds__(256) void scan1_k(const int* __restrict__ deg,
                                               int* __restrict__ off, int* __restrict__ bsum) {
    __shared__ int s[256];
    int t = threadIdx.x, i = blockIdx.x * 256 + t;
    int v = (i < NN) ? deg[i] : 0;
    s[t] = v;
    __syncthreads();
    #pragma unroll
    for (int ofs = 1; ofs < 256; ofs <<= 1) {
        int a = (t >= ofs) ? s[t - ofs] : 0;
        __syncthreads();
        s[t] += a;
        __syncthreads();
    }
    if (i < NN) off[i] = s[t] - v;
    if (t == 255) bsum[blockIdx.x] = s[255];
}

// scan the 391 block sums (single block, 512 threads)
__global__ __launch_bounds__(512) void scan2_k(int* __restrict__ bsum) {
    __shared__ int s[512];
    int t = threadIdx.x;
    int v = (t < NB) ? bsum[t] : 0;
    s[t] = v;
    __syncthreads();
    #pragma unroll
    for (int ofs = 1; ofs < 512; ofs <<= 1) {
        int a = (t >= ofs) ? s[t - ofs] : 0;
        __syncthreads();
        s[t] += a;
        __syncthreads();
    }
    if (t < NB) bsum[t] = s[t] - v;
}

// add scanned block sums; init scatter cursors
__global__ __launch_bounds__(256) void scan3_k(int* __restrict__ off, const int* __restrict__ bsum,
                                               int* __restrict__ cur) {
    int i = blockIdx.x * 256 + threadIdx.x;
    if (i >= NN) return;
    int v = off[i] + bsum[blockIdx.x];
    off[i] = v;
    cur[i] = v;
}

// scatter packed {src, u} into dst-buckets
__global__ __launch_bounds__(256) void scatter_k(const int* __restrict__ ei, const float* __restrict__ ea,
                                                 int* __restrict__ cur, int2* __restrict__ pk) {
    int e = blockIdx.x * 256 + threadIdx.x;
    if (e >= NE) return;
    int s = ei[e];
    int d = ei[NE + e];
    float u = fminf(fmaxf(ea[e], 0.f), 1.f);
    int p = atomicAdd(cur + d, 1);
    pk[p] = make_int2(s, __float_as_int(u));
}

// ---------------- layer-1 node transform: y01 interleaved [n][ y0(32) | y1(32) ], xr
__global__ __launch_bounds__(256) void transform1_k(
    const float* __restrict__ x, const float* __restrict__ W, const float* __restrict__ R,
    float* __restrict__ y01, float* __restrict__ xr)
{
    __shared__ float W0s[1024], W1s[1024], Rs[1024];
    __shared__ float xs[32 * 33];
    int tid = threadIdx.x;
    for (int i = tid; i < 1024; i += 256) {
        W0s[i] = W[i];
        W1s[i] = W[1024 + i];
        Rs[i]  = R[i];
    }
    int nb = blockIdx.x * 32;
    for (int i = tid; i < 1024; i += 256) {
        int n = nb + (i >> 5);
        xs[(i >> 5) * 33 + (i & 31)] = (n < NN) ? x[n * 32 + (i & 31)] : 0.f;
    }
    __syncthreads();
    int local = tid >> 3, c = tid & 7;            // 32 nodes/block, 8 lanes/node
    int n = nb + local;
    float4 a0 = make_float4(0.f, 0.f, 0.f, 0.f), a1 = a0, a2 = a0;
    #pragma unroll
    for (int k = 0; k < 32; k++) {
        float xk = xs[local * 33 + k];
        float4 w0 = ((const float4*)W0s)[k * 8 + c];
        float4 w1 = ((const float4*)W1s)[k * 8 + c];
        float4 r  = ((const float4*)Rs)[k * 8 + c];
        FMA4(a0, xk, w0); FMA4(a1, xk, w1); FMA4(a2, xk, r);
    }
    if (n < NN) {
        ((float4*)y01)[n * 16 + c]     = a0;
        ((float4*)y01)[n * 16 + 8 + c] = a1;
        ((float4*)xr)[n * 8 + c]       = a2;
    }
}

// ---------------- layer-1 aggregate + mean + root + bias + relu -> h (in place over xr)
__global__ __launch_bounds__(256) void agg1_k(
    const int* __restrict__ off, const int* __restrict__ deg, const int2* __restrict__ pk,
    const float* __restrict__ y01, const float* __restrict__ b, float* __restrict__ hx)
{
    int n = blockIdx.x * 8 + (threadIdx.x >> 5);  // 8 nodes/block, 32 lanes/node
    int f = threadIdx.x & 31;
    if (n >= NN) return;
    int st = off[n], dg = deg[n];
    float acc = 0.f;
    for (int base = 0; base < dg; base += 32) {
        int rem = dg - base;
        int2 p = make_int2(0, 0);
        if (f < rem) p = pk[st + base + f];       // coalesced chunk load
        int cnt = rem < 32 ? rem : 32;
        for (int k = 0; k < cnt; k++) {
            int   src = __shfl(p.x, k, 32);
            float u   = __int_as_float(__shfl(p.y, k, 32));
            float a = y01[(size_t)src * 64 + f];
            float bb = y01[(size_t)src * 64 + 32 + f];
            acc += (1.f - u) * a + u * bb;
        }
    }
    float hv = acc / fmaxf((float)dg, 1.f) + hx[n * 32 + f] + b[f];
    hx[n * 32 + f] = fmaxf(hv, 0.f);
}

// ---------------- layer-2 node transform: z01 interleaved [n][ z0(16) | z1(16) ], hr
__global__ __launch_bounds__(256) void transform2_k(
    const float* __restrict__ h, const float* __restrict__ W, const float* __restrict__ R,
    float* __restrict__ z01, float* __restrict__ hr)
{
    __shared__ float W0s[512], W1s[512], Rs[512];
    __shared__ float xs[64 * 33];
    int tid = threadIdx.x;
    for (int i = tid; i < 512; i += 256) {
        W0s[i] = W[i];
        W1s[i] = W[512 + i];
        Rs[i]  = R[i];
    }
    int nb = blockIdx.x * 64;
    for (int i = tid; i < 2048; i += 256) {
        int n = nb + (i >> 5);
        xs[(i >> 5) * 33 + (i & 31)] = (n < NN) ? h[n * 32 + (i & 31)] : 0.f;
    }
    __syncthreads();
    int local = tid >> 2, c = tid & 3;            // 64 nodes/block, 4 lanes/node
    int n = nb + local;
    float4 a0 = make_float4(0.f, 0.f, 0.f, 0.f), a1 = a0, a2 = a0;
    #pragma unroll
    for (int k = 0; k < 32; k++) {
        float xk = xs[local * 33 + k];
        float4 w0 = ((const float4*)W0s)[k * 4 + c];
        float4 w1 = ((const float4*)W1s)[k * 4 + c];
        float4 r  = ((const float4*)Rs)[k * 4 + c];
        FMA4(a0, xk, w0); FMA4(a1, xk, w1); FMA4(a2, xk, r);
    }
    if (n < NN) {
        ((float4*)z01)[n * 8 + c]     = a0;
        ((float4*)z01)[n * 8 + 4 + c] = a1;
        ((float4*)hr)[n * 4 + c]      = a2;
    }
}

// ---------------- layer-2 aggregate + mean + root + bias + log_softmax -> out
__global__ __launch_bounds__(256) void agg2_k(
    const int* __restrict__ off, const int* __restrict__ deg, const int2* __restrict__ pk,
    const float* __restrict__ z01, const float* __restrict__ hr, const float* __restrict__ b,
    float* __restrict__ out)
{
    int n = blockIdx.x * 16 + (threadIdx.x >> 4); // 16 nodes/block, 16 lanes/node
    int f = threadIdx.x & 15;
    if (n >= NN) return;
    int st = off[n], dg = deg[n];
    float acc = 0.f;
    for (int base = 0; base < dg; base += 16) {
        int rem = dg - base;
        int2 p = make_int2(0, 0);
        if (f < rem) p = pk[st + base + f];
        int cnt = rem < 16 ? rem : 16;
        for (int k = 0; k < cnt; k++) {
            int   src = __shfl(p.x, k, 16);
            float u   = __int_as_float(__shfl(p.y, k, 16));
            float a  = z01[(size_t)src * 32 + f];
            float bb = z01[(size_t)src * 32 + 16 + f];
            acc += (1.f - u) * a + u * bb;
        }
    }
    float o = acc / fmaxf((float)dg, 1.f) + hr[n * 16 + f] + b[f];
    // log_softmax across the 16 lanes of this node
    float m = o;
    #pragma unroll
    for (int ofs = 8; ofs; ofs >>= 1) m = fmaxf(m, __shfl_xor(m, ofs, 16));
    float ex = expf(o - m), sm = ex;
    #pragma unroll
    for (int ofs = 8; ofs; ofs >>= 1) sm += __shfl_xor(sm, ofs, 16);
    out[n * 16 + f] = o - (m + logf(sm));
}

extern "C" void kernel_launch(void* const* d_in, const int* in_sizes, int n_in,
                              void* d_out, int out_size, void* d_ws, size_t ws_size,
                              hipStream_t stream) {
    const float* x     = (const float*)d_in[0];
    const int*   ei    = (const int*)d_in[1];     // [2, NE]
    const float* ea    = (const float*)d_in[2];   // [NE, 1]
    const float* W1    = (const float*)d_in[3];
    const float* root1 = (const float*)d_in[4];
    const float* b1    = (const float*)d_in[5];
    const float* W2    = (const float*)d_in[6];
    const float* root2 = (const float*)d_in[7];
    const float* b2    = (const float*)d_in[8];
    float* out = (float*)d_out;

    // workspace layout (float units)
    float* ws = (float*)d_ws;
    int*  off  = (int*)ws;                                   // NN
    int*  deg  = (int*)(ws + NN);                            // NN
    int*  cur  = (int*)(ws + 2 * (size_t)NN);                // NN
    int*  bsum = (int*)(ws + 3 * (size_t)NN);                // 1024
    int2* pk   = (int2*)(ws + 3 * (size_t)NN + 1024);        // NE int2 (8B-aligned)
    float* y01 = ws + 3 * (size_t)NN + 1024 + 2 * (size_t)NE; // NN*64
    float* xr_h = y01 + (size_t)NN * 64;                     // NN*32
    float* z01 = y01;                                        // NN*32 (reuse)
    float* hr  = y01 + (size_t)NN * 32;                      // NN*16 (reuse)

    hipMemsetAsync(deg, 0, (size_t)NN * sizeof(int), stream);

    // CSR build (reused by both layers)
    hist_k   <<<(NE + 255) / 256, 256, 0, stream>>>(ei, deg);
    scan1_k  <<<NB, 256, 0, stream>>>(deg, off, bsum);
    scan2_k  <<<1, 512, 0, stream>>>(bsum);
    scan3_k  <<<NB, 256, 0, stream>>>(off, bsum, cur);
    scatter_k<<<(NE + 255) / 256, 256, 0, stream>>>(ei, ea, cur, pk);

    // layer 1
    transform1_k<<<(NN + 31) / 32, 256, 0, stream>>>(x, W1, root1, y01, xr_h);
    agg1_k<<<(NN + 7) / 8, 256, 0, stream>>>(off, deg, pk, y01, b1, xr_h);

    // layer 2
    transform2_k<<<(NN + 63) / 64, 256, 0, stream>>>(xr_h, W2, root2, z01, hr);
    agg2_k<<<(NN + 15) / 16, 256, 0, stream>>>(off, deg, pk, z01, hr, b2, out);
}